// Round 1
// baseline (473.258 us; speedup 1.0000x reference)
//
#include <hip/hip_runtime.h>
#include <hip/hip_bf16.h>

#define N_NODES 100000
#define N_EDGES 1600000
#define D_FEAT 50
#define ALPHA 0.1f

// out[i] = ALPHA * h[i]  (5M elements)
__global__ void init_out_kernel(const float* __restrict__ h,
                                float* __restrict__ out,
                                int n) {
    int idx = blockIdx.x * blockDim.x + threadIdx.x;
    if (idx < n) {
        out[idx] = ALPHA * h[idx];
    }
}

// One thread per (edge, feature). 50 consecutive threads share an edge so
// x-reads and atomic destinations are contiguous 200B runs.
__global__ void scatter_kernel(const float* __restrict__ x,
                               const float* __restrict__ vals,
                               const int* __restrict__ rows,
                               const int* __restrict__ cols,
                               float* __restrict__ out) {
    long long idx = (long long)blockIdx.x * blockDim.x + threadIdx.x;
    long long total = (long long)N_EDGES * D_FEAT;
    if (idx >= total) return;
    int e = (int)(idx / D_FEAT);
    int d = (int)(idx % D_FEAT);
    int r = rows[e];
    int c = cols[e];
    float v = vals[e];
    float contrib = (1.0f - ALPHA) * v * x[(long long)c * D_FEAT + d];
    atomicAdd(&out[(long long)r * D_FEAT + d], contrib);
}

extern "C" void kernel_launch(void* const* d_in, const int* in_sizes, int n_in,
                              void* d_out, int out_size, void* d_ws, size_t ws_size,
                              hipStream_t stream) {
    const float* x        = (const float*)d_in[0];
    const float* h        = (const float*)d_in[1];
    const float* adj_vals = (const float*)d_in[2];
    const int*   adj_rows = (const int*)d_in[3];
    const int*   adj_cols = (const int*)d_in[4];
    float* out = (float*)d_out;

    int n_out = N_NODES * D_FEAT;  // 5,000,000
    {
        int block = 256;
        int grid = (n_out + block - 1) / block;
        init_out_kernel<<<grid, block, 0, stream>>>(h, out, n_out);
    }
    {
        long long total = (long long)N_EDGES * D_FEAT;  // 80,000,000
        int block = 256;
        long long grid = (total + block - 1) / block;
        scatter_kernel<<<(int)grid, block, 0, stream>>>(x, adj_vals, adj_rows, adj_cols, out);
    }
}